// Round 5
// baseline (42298.700 us; speedup 1.0000x reference)
//
#include <hip/hip_runtime.h>
#include <cstdint>
#include <cstddef>

#define DEVINL __device__ __forceinline__

typedef unsigned short ushort_t;
typedef unsigned long long u64;
typedef __attribute__((ext_vector_type(8))) short bf16x8;
typedef __attribute__((ext_vector_type(8))) _Float16 f16x8;
typedef __attribute__((ext_vector_type(4))) float f32x4;

namespace {
constexpr int kB = 64, kH = 1024, kG4 = 4096, kV = 32000;
constexpr int NBLK = 512, NTHR = 512;
constexpr int NKC = 16;
constexpr int EBLK = 500;
constexpr int START_INDEX = 1;
constexpr float GAP_TRIG = 1e-3f;
constexpr float CAND_THR = 2.5e-4f;
}

struct WsPtrs {
  float* P;
  float* c0s; float* c1s;
  float* h1s;
  ushort_t *h0hi, *h0lo;
  ushort_t *h1hi, *h1lo;
  ushort_t *h1hi16, *h1lo16;
  u64* btop;
  int* lastArr;
  unsigned* bar;
  ushort_t* img;
};

// ---------- agent-scope (sc1) data accessors: per-address cross-XCD coherence ----------
DEVINL void stf(float* p, float v) { __hip_atomic_store(p, v, __ATOMIC_RELAXED, __HIP_MEMORY_SCOPE_AGENT); }
DEVINL float ldf(const float* p) { return __hip_atomic_load((float*)p, __ATOMIC_RELAXED, __HIP_MEMORY_SCOPE_AGENT); }
DEVINL void stu32(unsigned* p, unsigned v) { __hip_atomic_store(p, v, __ATOMIC_RELAXED, __HIP_MEMORY_SCOPE_AGENT); }
DEVINL void st64(u64* p, u64 v) { __hip_atomic_store(p, v, __ATOMIC_RELAXED, __HIP_MEMORY_SCOPE_AGENT); }
DEVINL u64 ld64(const u64* p) { return __hip_atomic_load((u64*)p, __ATOMIC_RELAXED, __HIP_MEMORY_SCOPE_AGENT); }
DEVINL void sti(int* p, int v) { __hip_atomic_store(p, v, __ATOMIC_RELAXED, __HIP_MEMORY_SCOPE_AGENT); }
DEVINL int ldi(const int* p) { return __hip_atomic_load((int*)p, __ATOMIC_RELAXED, __HIP_MEMORY_SCOPE_AGENT); }

// ---------- numeric helpers ----------
DEVINL ushort_t bf16rne(float f) {
  unsigned u = __float_as_uint(f);
  unsigned r = (u + 0x7FFFu + ((u >> 16) & 1u)) >> 16;
  return (ushort_t)r;
}
DEVINL float bf2f(ushort_t h) { return __uint_as_float(((unsigned)h) << 16); }
DEVINL ushort_t f16bits(_Float16 h) { union { _Float16 h; ushort_t u; } c; c.h = h; return c.u; }

DEVINL void packbf16x8(const float* f, uint4& hi, uint4& lo) {
  unsigned hh[8], ll[8];
  #pragma unroll
  for (int j = 0; j < 8; ++j) {
    ushort_t h = bf16rne(f[j]);
    hh[j] = h;
    ll[j] = bf16rne(f[j] - bf2f(h));
  }
  hi.x = hh[0] | (hh[1] << 16); hi.y = hh[2] | (hh[3] << 16);
  hi.z = hh[4] | (hh[5] << 16); hi.w = hh[6] | (hh[7] << 16);
  lo.x = ll[0] | (ll[1] << 16); lo.y = ll[2] | (ll[3] << 16);
  lo.z = ll[4] | (ll[5] << 16); lo.w = ll[6] | (ll[7] << 16);
}
DEVINL uint4 packf16x8(const float* f) {
  union { ushort_t u[8]; uint4 v; } r;
  #pragma unroll
  for (int j = 0; j < 8; ++j) r.u[j] = f16bits((_Float16)f[j]);
  return r.v;
}

DEVINL u64 packKey(float v, unsigned idx) {
  unsigned u = __float_as_uint(v);
  u = (u & 0x80000000u) ? ~u : (u | 0x80000000u);
  return ((u64)u << 32) | (0xFFFFFFFFu - idx);
}
DEVINL float keyVal(u64 k) {
  unsigned u = (unsigned)(k >> 32);
  u = (u & 0x80000000u) ? (u & 0x7FFFFFFFu) : ~u;
  return __uint_as_float(u);
}
DEVINL int keyIdx(u64 k) { return (int)(0xFFFFFFFFu - (unsigned)(k & 0xFFFFFFFFull)); }

DEVINL void topMerge(u64& a0, u64& a1, u64& a2, u64& a3,
                     u64 b0, u64 b1, u64 b2, u64 b3) {
  u64 y0 = a0 > b3 ? a0 : b3;
  u64 y1 = a1 > b2 ? a1 : b2;
  u64 y2 = a2 > b1 ? a2 : b1;
  u64 y3 = a3 > b0 ? a3 : b0;
  u64 t;
  t = y0 > y2 ? y0 : y2; y2 = y0 > y2 ? y2 : y0; y0 = t;
  t = y1 > y3 ? y1 : y3; y3 = y1 > y3 ? y3 : y1; y1 = t;
  t = y0 > y1 ? y0 : y1; y1 = y0 > y1 ? y1 : y0; y0 = t;
  t = y2 > y3 ? y2 : y3; y3 = y2 > y3 ? y3 : y2; y2 = t;
  a0 = y0; a1 = y1; a2 = y2; a3 = y3;
}

// ---------- hierarchical grid barrier: monotonic, no cache-wide fences ----------
// layout (dwords in bar): grpc[g] at g*32 (g<32); rootc at 1024; gen at 1056; mir[g] at 1088+g*32
DEVINL void gbar(unsigned* bar, int bid, unsigned epoch) {
  __syncthreads();
  if (threadIdx.x == 0) {
    const int g = bid >> 4;
    unsigned* grpc = bar + g * 32;
    unsigned* rootc = bar + 1024;
    unsigned* gen  = bar + 1056;
    unsigned* mir  = bar + 1088 + g * 32;
    unsigned o = __hip_atomic_fetch_add(grpc, 1u, __ATOMIC_ACQ_REL, __HIP_MEMORY_SCOPE_AGENT);
    if ((o & 15u) == 15u) {
      // group-last: arrive at root; become this group's release leader
      unsigned ro = __hip_atomic_fetch_add(rootc, 1u, __ATOMIC_ACQ_REL, __HIP_MEMORY_SCOPE_AGENT);
      if ((ro & 31u) == 31u)
        __hip_atomic_store(gen, epoch + 1u, __ATOMIC_RELEASE, __HIP_MEMORY_SCOPE_AGENT);
      while (__hip_atomic_load(gen, __ATOMIC_ACQUIRE, __HIP_MEMORY_SCOPE_AGENT) <= epoch)
        __builtin_amdgcn_s_sleep(8);
      __hip_atomic_store(mir, epoch + 1u, __ATOMIC_RELEASE, __HIP_MEMORY_SCOPE_AGENT);
    } else {
      while (__hip_atomic_load(mir, __ATOMIC_ACQUIRE, __HIP_MEMORY_SCOPE_AGENT) <= epoch)
        __builtin_amdgcn_s_sleep(8);
    }
  }
  __syncthreads();
}

DEVINL f32x4 mfbf(bf16x8 a, bf16x8 b, f32x4 c) {
  return __builtin_amdgcn_mfma_f32_16x16x32_bf16(a, b, c, 0, 0, 0);
}
DEVINL f32x4 mff16(f16x8 a, f16x8 b, f32x4 c) {
  return __builtin_amdgcn_mfma_f32_16x16x32_f16(a, b, c, 0, 0, 0);
}

// ---------- pre-pass: Wout fp32 -> swizzled fp16 image ----------
__global__ __launch_bounds__(256) void wout_prepass(const float* __restrict__ Wout,
                                                    ushort_t* __restrict__ img) {
  int U = blockIdx.x * 256 + threadIdx.x;
  if (U >= EBLK * 16 * 512) return;
  int unit = U & 511, ch = (U >> 9) & 15, vb = U >> 13;
  int row = unit >> 3, j = unit & 7;
  int v = vb * 64 + row;
  int k = ch * 64 + ((j ^ (row & 7)) << 3);
  const float* s = Wout + (size_t)v * kH + k;
  float4 f0 = *(const float4*)s;
  float4 f1 = *(const float4*)(s + 4);
  float ff[8] = {f0.x, f0.y, f0.z, f0.w, f1.x, f1.y, f1.z, f1.w};
  *(uint4*)(img + (size_t)U * 8) = packf16x8(ff);
}

// ---------- gate GEMM phase: block (kc,nt): [64b x 128n] over 128k, bf16x3 ----------
DEVINL void gates_phase(int bid, int tid,
                        const float* __restrict__ Wx, const float* __restrict__ Wh,
                        const float* __restrict__ emb, const int* last_l,
                        const ushort_t* __restrict__ xaHi, const ushort_t* __restrict__ xaLo,
                        const ushort_t* __restrict__ xbHi, const ushort_t* __restrict__ xbLo,
                        float* __restrict__ P,
                        ushort_t* sXh, ushort_t* sXl, ushort_t* sWh, ushort_t* sWl) {
  const int kc = bid >> 5, nt = bid & 31;
  const int wv = tid >> 6, lane = tid & 63;
  const int l15 = lane & 15, l4 = lane >> 4;
  const bool lowk = kc < 8;
  const bool xcvt = lowk && (emb != nullptr);
  f32x4 acc[4];
  #pragma unroll
  for (int mt = 0; mt < 4; ++mt) acc[mt] = (f32x4){0.f, 0.f, 0.f, 0.f};

  const int xrow = tid >> 3, xj = tid & 7;
  const int wr1 = xrow + 64;

  uint4 xvh, xvl;
  float xf[8], wf0[8], wf1[8];

  auto loadChunk = [&](int ch) {
    const int kk = kc * 128 + ch * 64;
    const int ksrc = lowk ? kk : kk - kH;
    const int xks = ksrc + ((xj ^ (xrow & 7)) << 3);
    if (xcvt) {
      const float* s = emb + (size_t)last_l[xrow] * kH + xks;
      float4 a0 = *(const float4*)s; float4 a1 = *(const float4*)(s + 4);
      xf[0]=a0.x; xf[1]=a0.y; xf[2]=a0.z; xf[3]=a0.w;
      xf[4]=a1.x; xf[5]=a1.y; xf[6]=a1.z; xf[7]=a1.w;
    } else {
      const ushort_t* ph = lowk ? xaHi : xbHi;
      const ushort_t* pl = lowk ? xaLo : xbLo;
      size_t go = (size_t)xrow * kH + xks;
      u64 a = ld64((const u64*)(ph + go));
      u64 b = ld64((const u64*)(ph + go + 4));
      xvh.x = (unsigned)a; xvh.y = (unsigned)(a >> 32);
      xvh.z = (unsigned)b; xvh.w = (unsigned)(b >> 32);
      a = ld64((const u64*)(pl + go));
      b = ld64((const u64*)(pl + go + 4));
      xvl.x = (unsigned)a; xvl.y = (unsigned)(a >> 32);
      xvl.z = (unsigned)b; xvl.w = (unsigned)(b >> 32);
    }
    const float* Wsel = lowk ? Wx : Wh;
    {
      const int ks0 = ksrc + ((xj ^ (xrow & 7)) << 3);
      const float* s = Wsel + (size_t)(nt * 128 + xrow) * kH + ks0;
      float4 a0 = *(const float4*)s; float4 a1 = *(const float4*)(s + 4);
      wf0[0]=a0.x; wf0[1]=a0.y; wf0[2]=a0.z; wf0[3]=a0.w;
      wf0[4]=a1.x; wf0[5]=a1.y; wf0[6]=a1.z; wf0[7]=a1.w;
      const int ks1 = ksrc + ((xj ^ (wr1 & 7)) << 3);
      const float* s2 = Wsel + (size_t)(nt * 128 + wr1) * kH + ks1;
      float4 b0 = *(const float4*)s2; float4 b1 = *(const float4*)(s2 + 4);
      wf1[0]=b0.x; wf1[1]=b0.y; wf1[2]=b0.z; wf1[3]=b0.w;
      wf1[4]=b1.x; wf1[5]=b1.y; wf1[6]=b1.z; wf1[7]=b1.w;
    }
  };

  loadChunk(0);
  #pragma unroll 1
  for (int ch = 0; ch < 2; ++ch) {
    __syncthreads();
    if (xcvt) packbf16x8(xf, xvh, xvl);
    *(uint4*)&sXh[tid * 8] = xvh;
    *(uint4*)&sXl[tid * 8] = xvl;
    { uint4 h, l; packbf16x8(wf0, h, l);
      *(uint4*)&sWh[tid * 8] = h; *(uint4*)&sWl[tid * 8] = l; }
    { uint4 h, l; packbf16x8(wf1, h, l);
      *(uint4*)&sWh[(tid + 512) * 8] = h; *(uint4*)&sWl[(tid + 512) * 8] = l; }
    __syncthreads();
    if (ch == 0) loadChunk(1);   // overlap next chunk's loads with MFMA below
    #pragma unroll
    for (int ks = 0; ks < 2; ++ks) {
      bf16x8 ah[4], al[4];
      #pragma unroll
      for (int mt = 0; mt < 4; ++mt) {
        int r = mt * 16 + l15;
        int off = r * 64 + (((ks * 4 + l4) ^ (r & 7)) << 3);
        ah[mt] = *(const bf16x8*)&sXh[off];
        al[mt] = *(const bf16x8*)&sXl[off];
      }
      int rn = wv * 16 + l15;
      int offB = rn * 64 + (((ks * 4 + l4) ^ (rn & 7)) << 3);
      bf16x8 bh = *(const bf16x8*)&sWh[offB];
      bf16x8 bl = *(const bf16x8*)&sWl[offB];
      #pragma unroll
      for (int mt = 0; mt < 4; ++mt) {
        acc[mt] = mfbf(ah[mt], bh, acc[mt]);
        acc[mt] = mfbf(al[mt], bh, acc[mt]);
        acc[mt] = mfbf(ah[mt], bl, acc[mt]);
      }
    }
  }
  const int n = nt * 128 + wv * 16 + l15;
  #pragma unroll
  for (int mt = 0; mt < 4; ++mt)
    #pragma unroll
    for (int r = 0; r < 4; ++r) {
      int b = mt * 16 + l4 * 4 + r;
      stf(&P[((size_t)kc * kB + b) * kG4 + n], acc[mt][r]);
    }
}

// ---------- elementwise LSTM cell: 64 blocks x 512 thr x 2 units ----------
DEVINL void elem_phase2(int bid, int tid, const float* __restrict__ P,
                        const float* __restrict__ bi, const float* __restrict__ bh,
                        float* cs, ushort_t* hhi, ushort_t* hlo,
                        ushort_t* hhi16, ushort_t* hlo16, float* hf32s) {
  const int gt0 = bid * 1024 + tid * 2;
  const int b = gt0 >> 10, u0 = gt0 & 1023;
  double s[2][4];
  #pragma unroll
  for (int gi = 0; gi < 4; ++gi) {
    const int n = gi * kH + u0;
    double a0 = (double)bi[n] + (double)bh[n];
    double a1 = (double)bi[n + 1] + (double)bh[n + 1];
    #pragma unroll
    for (int c = 0; c < NKC; ++c) {
      union { u64 q; float f[2]; } uq;
      uq.q = ld64((const u64*)(P + ((size_t)c * kB + b) * kG4 + n));
      a0 += (double)uq.f[0]; a1 += (double)uq.f[1];
    }
    s[0][gi] = a0; s[1][gi] = a1;
  }
  float hf[2];
  #pragma unroll
  for (int q = 0; q < 2; ++q) {
    const int gt = gt0 + q;
    double c = (double)cs[gt];
    double ig = 1.0 / (1.0 + exp(-s[q][0]));
    double fg = 1.0 / (1.0 + exp(-s[q][1]));
    double gg = tanh(s[q][2]);
    double og = 1.0 / (1.0 + exp(-s[q][3]));
    double cn = fg * c + ig * gg;
    cs[gt] = (float)cn;                   // block-private: normal store
    hf[q] = (float)(og * tanh(cn));
  }
  ushort_t h0 = bf16rne(hf[0]), h1 = bf16rne(hf[1]);
  stu32((unsigned*)hhi + (gt0 >> 1), (unsigned)h0 | ((unsigned)h1 << 16));
  ushort_t l0 = bf16rne(hf[0] - bf2f(h0)), l1 = bf16rne(hf[1] - bf2f(h1));
  stu32((unsigned*)hlo + (gt0 >> 1), (unsigned)l0 | ((unsigned)l1 << 16));
  if (hhi16) {
    _Float16 a = (_Float16)hf[0], bq = (_Float16)hf[1];
    stu32((unsigned*)hhi16 + (gt0 >> 1), (unsigned)f16bits(a) | ((unsigned)f16bits(bq) << 16));
    _Float16 la = (_Float16)(hf[0] - (float)a), lb = (_Float16)(hf[1] - (float)bq);
    stu32((unsigned*)hlo16 + (gt0 >> 1), (unsigned)f16bits(la) | ((unsigned)f16bits(lb) << 16));
    union { float f[2]; u64 q; } w; w.f[0] = hf[0]; w.f[1] = hf[1];
    st64((u64*)(hf32s + gt0), w.q);
  }
}

__global__ __launch_bounds__(NTHR, 4) void stack_lstm_persistent(
    const float* __restrict__ hidden, const float* __restrict__ emb,
    const float* __restrict__ Wih0, const float* __restrict__ Whh0,
    const float* __restrict__ bih0, const float* __restrict__ bhh0,
    const float* __restrict__ Wih1, const float* __restrict__ Whh1,
    const float* __restrict__ bih1, const float* __restrict__ bhh1,
    const float* __restrict__ Wout, const float* __restrict__ bout,
    float* __restrict__ out, int T, int pre, WsPtrs ws) {
  __shared__ ushort_t sXh[64 * 64], sXl[64 * 64];
  __shared__ ushort_t sWh[128 * 64], sWl[128 * 64];
  __shared__ u64 sRed[1024];
  __shared__ int last_l[kB];

  const int tid = threadIdx.x;
  const int bid = blockIdx.x;
  const int wv = tid >> 6, lane = tid & 63;
  const int l15 = lane & 15, l4 = lane >> 4;
  unsigned ep = 0;

  // ---- init state (same mapping as elem blocks so c-state stays block-private) ----
  if (bid < 64) {
    const int gt0 = bid * 1024 + tid * 2;
    float2 h0p = *(const float2*)(hidden + gt0);
    float2 h1p = *(const float2*)(hidden + kB * kH + gt0);
    ushort_t a = bf16rne(h0p.x), b2 = bf16rne(h0p.y);
    stu32((unsigned*)ws.h0hi + (gt0 >> 1), (unsigned)a | ((unsigned)b2 << 16));
    ushort_t la = bf16rne(h0p.x - bf2f(a)), lb = bf16rne(h0p.y - bf2f(b2));
    stu32((unsigned*)ws.h0lo + (gt0 >> 1), (unsigned)la | ((unsigned)lb << 16));
    a = bf16rne(h1p.x); b2 = bf16rne(h1p.y);
    stu32((unsigned*)ws.h1hi + (gt0 >> 1), (unsigned)a | ((unsigned)b2 << 16));
    la = bf16rne(h1p.x - bf2f(a)); lb = bf16rne(h1p.y - bf2f(b2));
    stu32((unsigned*)ws.h1lo + (gt0 >> 1), (unsigned)la | ((unsigned)lb << 16));
    _Float16 fa = (_Float16)h1p.x, fb = (_Float16)h1p.y;
    stu32((unsigned*)ws.h1hi16 + (gt0 >> 1), (unsigned)f16bits(fa) | ((unsigned)f16bits(fb) << 16));
    _Float16 fla = (_Float16)(h1p.x - (float)fa), flb = (_Float16)(h1p.y - (float)fb);
    stu32((unsigned*)ws.h1lo16 + (gt0 >> 1), (unsigned)f16bits(fla) | ((unsigned)f16bits(flb) << 16));
    union { float f[2]; u64 q; } w; w.f[0] = h1p.x; w.f[1] = h1p.y;
    st64((u64*)(ws.h1s + gt0), w.q);
    *(float2*)(ws.c0s + gt0) = make_float2(0.f, 0.f);
    *(float2*)(ws.c1s + gt0) = make_float2(0.f, 0.f);
  }
  gbar(ws.bar, bid, ep); ++ep;

  #pragma unroll 1
  for (int t = 0; t < T; ++t) {
    // ===== A: layer-0 gates -> P =====
    if (tid < kB) last_l[tid] = (t == 0) ? START_INDEX : ldi(ws.lastArr + (t - 1) * kB + tid);
    __syncthreads();
    gates_phase(bid, tid, Wih0, Whh0, emb, last_l,
                nullptr, nullptr, ws.h0hi, ws.h0lo,
                ws.P, sXh, sXl, sWh, sWl);
    gbar(ws.bar, bid, ep); ++ep;

    // ===== B: elem0 =====
    if (bid < 64)
      elem_phase2(bid, tid, ws.P, bih0, bhh0, ws.c0s,
                  ws.h0hi, ws.h0lo, nullptr, nullptr, nullptr);
    gbar(ws.bar, bid, ep); ++ep;

    // ===== C: layer-1 gates -> P =====
    gates_phase(bid, tid, Wih1, Whh1, nullptr, last_l,
                ws.h0hi, ws.h0lo, ws.h1hi, ws.h1lo,
                ws.P, sXh, sXl, sWh, sWl);
    gbar(ws.bar, bid, ep); ++ep;

    // ===== D: elem1 =====
    if (bid < 64)
      elem_phase2(bid, tid, ws.P, bih1, bhh1, ws.c1s,
                  ws.h1hi, ws.h1lo, ws.h1hi16, ws.h1lo16, ws.h1s);
    gbar(ws.bar, bid, ep); ++ep;

    // ===== E: logits [64b x 64v] per block, fp16 x2 MFMA, top-4 =====
    if (bid < EBLK) {
      const int v0 = bid * 64;
      const int bhalf = wv >> 2, vg = wv & 3;
      f32x4 acc2[2];
      acc2[0] = (f32x4){0.f, 0.f, 0.f, 0.f};
      acc2[1] = (f32x4){0.f, 0.f, 0.f, 0.f};
      ushort_t* wbuf = sWh;
      const int row = tid >> 3, j = tid & 7;
      uint4 wreg, xh, xl; float wfp[8];

      auto loadE = [&](int ch) {
        const int ks = ch * 64 + ((j ^ (row & 7)) << 3);
        if (pre) {
          wreg = *(const uint4*)(ws.img + (((size_t)bid * 16 + ch) * 512 + tid) * 8);
        } else {
          const float* s = Wout + (size_t)(v0 + row) * kH + ks;
          float4 a0 = *(const float4*)s; float4 a1 = *(const float4*)(s + 4);
          wfp[0]=a0.x; wfp[1]=a0.y; wfp[2]=a0.z; wfp[3]=a0.w;
          wfp[4]=a1.x; wfp[5]=a1.y; wfp[6]=a1.z; wfp[7]=a1.w;
        }
        size_t go = (size_t)row * kH + ks;
        u64 a = ld64((const u64*)(ws.h1hi16 + go));
        u64 b = ld64((const u64*)(ws.h1hi16 + go + 4));
        xh.x = (unsigned)a; xh.y = (unsigned)(a >> 32); xh.z = (unsigned)b; xh.w = (unsigned)(b >> 32);
        a = ld64((const u64*)(ws.h1lo16 + go));
        b = ld64((const u64*)(ws.h1lo16 + go + 4));
        xl.x = (unsigned)a; xl.y = (unsigned)(a >> 32); xl.z = (unsigned)b; xl.w = (unsigned)(b >> 32);
      };

      loadE(0);
      #pragma unroll 1
      for (int ch = 0; ch < 16; ++ch) {
        __syncthreads();
        if (!pre) wreg = packf16x8(wfp);
        *(uint4*)&wbuf[tid * 8] = wreg;
        *(uint4*)&sXh[tid * 8] = xh;
        *(uint4*)&sXl[tid * 8] = xl;
        __syncthreads();
        if (ch < 15) loadE(ch + 1);   // overlap with MFMA below
        #pragma unroll
        for (int ks2 = 0; ks2 < 2; ++ks2) {
          f16x8 xfh[2], xfl[2];
          #pragma unroll
          for (int mt = 0; mt < 2; ++mt) {
            int r = bhalf * 32 + mt * 16 + l15;
            int off = r * 64 + (((ks2 * 4 + l4) ^ (r & 7)) << 3);
            xfh[mt] = *(const f16x8*)&sXh[off];
            xfl[mt] = *(const f16x8*)&sXl[off];
          }
          int rn = vg * 16 + l15;
          int offB = rn * 64 + (((ks2 * 4 + l4) ^ (rn & 7)) << 3);
          f16x8 wfr = *(const f16x8*)&wbuf[offB];
          #pragma unroll
          for (int mt = 0; mt < 2; ++mt) {
            acc2[mt] = mff16(xfh[mt], wfr, acc2[mt]);
            acc2[mt] = mff16(xfl[mt], wfr, acc2[mt]);
          }
        }
      }
      // epilogue: bias, store, per-row top-4
      const unsigned vcol = v0 + vg * 16 + l15;
      float bo = bout[vcol];
      #pragma unroll
      for (int mt = 0; mt < 2; ++mt) {
        #pragma unroll
        for (int r = 0; r < 4; ++r) {
          float val = acc2[mt][r] + bo;
          int b = bhalf * 32 + mt * 16 + l4 * 4 + r;
          out[((size_t)b * T + t) * kV + vcol] = val;
          u64 t0 = packKey(val, vcol), t1 = 0, t2 = 0, t3 = 0;
          #pragma unroll
          for (int m = 1; m < 16; m <<= 1) {
            u64 o0 = __shfl_xor(t0, m, 16);
            u64 o1 = __shfl_xor(t1, m, 16);
            u64 o2 = __shfl_xor(t2, m, 16);
            u64 o3 = __shfl_xor(t3, m, 16);
            topMerge(t0, t1, t2, t3, o0, o1, o2, o3);
          }
          if (l15 == 0) {
            u64* d = &sRed[((size_t)b * 4 + vg) * 4];
            d[0] = t0; d[1] = t1; d[2] = t2; d[3] = t3;
          }
        }
      }
      __syncthreads();
      if (tid < kB) {
        const u64* s0 = &sRed[(size_t)tid * 16];
        u64 a0 = s0[0], a1 = s0[1], a2 = s0[2], a3 = s0[3];
        #pragma unroll
        for (int g = 1; g < 4; ++g)
          topMerge(a0, a1, a2, a3, s0[g * 4], s0[g * 4 + 1], s0[g * 4 + 2], s0[g * 4 + 3]);
        u64* d = ws.btop + ((size_t)tid * EBLK + bid) * 4;
        st64(&d[0], a0); st64(&d[1], a1); st64(&d[2], a2); st64(&d[3], a3);
      }
    }
    gbar(ws.bar, bid, ep); ++ep;

    // ===== F: global top-4 + exact fp64 rescue -> lastArr =====
    if (bid < kB) {
      const int b = bid;
      u64 a0 = 0, a1 = 0, a2 = 0, a3 = 0;
      if (tid < EBLK) {
        const u64* s = ws.btop + ((size_t)b * EBLK + tid) * 4;
        a0 = ld64(&s[0]); a1 = ld64(&s[1]); a2 = ld64(&s[2]); a3 = ld64(&s[3]);
      }
      #pragma unroll
      for (int m = 1; m < 64; m <<= 1) {
        u64 o0 = __shfl_xor(a0, m, 64);
        u64 o1 = __shfl_xor(a1, m, 64);
        u64 o2 = __shfl_xor(a2, m, 64);
        u64 o3 = __shfl_xor(a3, m, 64);
        topMerge(a0, a1, a2, a3, o0, o1, o2, o3);
      }
      if (lane == 0) {
        u64* d = &sRed[wv * 4];
        d[0] = a0; d[1] = a1; d[2] = a2; d[3] = a3;
      }
      __syncthreads();
      if (tid == 0) {
        u64 f0 = sRed[0], f1 = sRed[1], f2 = sRed[2], f3 = sRed[3];
        #pragma unroll
        for (int w = 1; w < 8; ++w)
          topMerge(f0, f1, f2, f3, sRed[w * 4], sRed[w * 4 + 1], sRed[w * 4 + 2], sRed[w * 4 + 3]);
        sRed[520] = f0; sRed[521] = f1; sRed[522] = f2; sRed[523] = f3;
        sRed[524] = (keyVal(f0) - keyVal(f1) < GAP_TRIG) ? 1ull : 0ull;
      }
      __syncthreads();
      u64 f0 = sRed[520], f1 = sRed[521], f2 = sRed[522], f3 = sRed[523];
      bool resc = sRed[524] != 0ull;
      __syncthreads();
      if (!resc) {
        if (tid == 0) sti(ws.lastArr + t * kB + b, keyIdx(f0));
      } else {
        int cand = tid >> 7, jj = tid & 127;
        int ci;
        if (cand == 0) ci = keyIdx(f0);
        else if (cand == 1) ci = keyIdx(f1);
        else if (cand == 2) ci = keyIdx(f2);
        else ci = keyIdx(f3);
        double s = 0.0;
        const float* h = ws.h1s + (size_t)b * kH;
        const float* wr = Wout + (size_t)ci * kH;
        #pragma unroll
        for (int q = 0; q < 8; ++q) {
          int u = jj * 8 + q;
          s += (double)ldf(h + u) * (double)wr[u];
        }
        double* sD = (double*)sRed;
        sD[cand * 128 + jj] = s;
        __syncthreads();
        for (int st = 64; st > 0; st >>= 1) {
          if (jj < st) sD[cand * 128 + jj] += sD[cand * 128 + jj + st];
          __syncthreads();
        }
        if (tid == 0) {
          float v1 = keyVal(f0);
          double best = sD[0] + (double)bout[keyIdx(f0)];
          int bi = keyIdx(f0);
          {
            double d = sD[128] + (double)bout[keyIdx(f1)];
            int i = keyIdx(f1);
            if (d > best || (d == best && i < bi)) { best = d; bi = i; }
          }
          if (keyVal(f2) > v1 - CAND_THR) {
            double d = sD[256] + (double)bout[keyIdx(f2)];
            int i = keyIdx(f2);
            if (d > best || (d == best && i < bi)) { best = d; bi = i; }
          }
          if (keyVal(f3) > v1 - CAND_THR) {
            double d = sD[384] + (double)bout[keyIdx(f3)];
            int i = keyIdx(f3);
            if (d > best || (d == best && i < bi)) { best = d; bi = i; }
          }
          sti(ws.lastArr + t * kB + b, bi);
        }
      }
    }
    gbar(ws.bar, bid, ep); ++ep;
  }
}

extern "C" void kernel_launch(void* const* d_in, const int* in_sizes, int n_in,
                              void* d_out, int out_size, void* d_ws, size_t ws_size,
                              hipStream_t stream) {
  (void)in_sizes; (void)n_in;
  const float* hidden = (const float*)d_in[0];
  const float* emb    = (const float*)d_in[1];
  const float* Wih0   = (const float*)d_in[2];
  const float* Whh0   = (const float*)d_in[3];
  const float* bih0   = (const float*)d_in[4];
  const float* bhh0   = (const float*)d_in[5];
  const float* Wih1   = (const float*)d_in[6];
  const float* Whh1   = (const float*)d_in[7];
  const float* bih1   = (const float*)d_in[8];
  const float* bhh1   = (const float*)d_in[9];
  const float* Wout   = (const float*)d_in[10];
  const float* bout   = (const float*)d_in[11];
  float* out = (float*)d_out;

  const int T = out_size / (kB * kV);
  if (T <= 0) return;

  char* w = (char*)d_ws;
  WsPtrs ws;
  ws.P      = (float*)w;    w += (size_t)NKC * kB * kG4 * 4;
  ws.c0s    = (float*)w;    w += (size_t)kB * kH * 4;
  ws.c1s    = (float*)w;    w += (size_t)kB * kH * 4;
  ws.h1s    = (float*)w;    w += (size_t)kB * kH * 4;
  ws.h0hi   = (ushort_t*)w; w += (size_t)kB * kH * 2;
  ws.h0lo   = (ushort_t*)w; w += (size_t)kB * kH * 2;
  ws.h1hi   = (ushort_t*)w; w += (size_t)kB * kH * 2;
  ws.h1lo   = (ushort_t*)w; w += (size_t)kB * kH * 2;
  ws.h1hi16 = (ushort_t*)w; w += (size_t)kB * kH * 2;
  ws.h1lo16 = (ushort_t*)w; w += (size_t)kB * kH * 2;
  ws.btop   = (u64*)w;      w += (size_t)kB * EBLK * 4 * 8;
  ws.lastArr = (int*)w;     w += (size_t)T * kB * 4;
  uintptr_t a = ((uintptr_t)w + 127) & ~(uintptr_t)127;
  ws.bar = (unsigned*)a;
  char* after_bar = (char*)a + 16384;

  const size_t imgBytes = (size_t)EBLK * 16 * 512 * 16;
  size_t used = (size_t)(after_bar - (char*)d_ws);
  int pre = (ws_size >= used + imgBytes + (1u << 20)) ? 1 : 0;
  ws.img = (ushort_t*)after_bar;

  hipMemsetAsync((void*)ws.bar, 0, 16384, stream);
  if (pre) {
    int units = EBLK * 16 * 512;
    hipLaunchKernelGGL(wout_prepass, dim3((units + 255) / 256), dim3(256), 0, stream,
                       Wout, ws.img);
  }
  hipLaunchKernelGGL(stack_lstm_persistent, dim3(NBLK), dim3(NTHR), 0, stream,
                     hidden, emb, Wih0, Whh0, bih0, bhh0,
                     Wih1, Whh1, bih1, bhh1, Wout, bout,
                     out, T, pre, ws);
}

// Round 6
// 19471.005 us; speedup vs baseline: 2.1724x; 2.1724x over previous
//
#include <hip/hip_runtime.h>
#include <cstdint>
#include <cstddef>

#define DEVINL __device__ __forceinline__

typedef unsigned short ushort_t;
typedef unsigned long long u64;
typedef __attribute__((ext_vector_type(8))) short bf16x8;
typedef __attribute__((ext_vector_type(4))) float f32x4;

namespace {
constexpr int kB = 64, kH = 1024, kG4 = 4096, kV = 32000;
constexpr int NBLK = 512, NTHR = 512;
constexpr int NKC = 8;            // K-split chunks (256 wide each)
constexpr int EBLK = 500;         // logits blocks: 500 x 64 vocab cols
constexpr int START_INDEX = 1;
constexpr float GAP_TRIG = 4e-3f;   // rescue trigger (bf16-single logits err ~5e-4)
constexpr float CAND_THR = 2e-3f;   // candidate inclusion window
}

struct WsPtrs {
  float* P;                         // [8][64][4096] gate partials
  float* c0s; float* c1s;           // [64][1024] cell states (block-private)
  float* h1s;                       // fp32 h1 (rescue)
  ushort_t *h0hi, *h0lo;            // bf16 hi/lo planes
  ushort_t *h1hi, *h1lo;
  u64* btop;                        // [64][500][4] per-block top-4
  int* lastArr;                     // [T][64]
  unsigned* bar;
  ushort_t* imgV;                   // Wout bf16 single-plane swizzled image
  ushort_t *imgGh, *imgGl;          // gate weights bf16 hi/lo swizzled images
};

// ---------- numeric helpers ----------
DEVINL ushort_t bf16rne(float f) {
  unsigned u = __float_as_uint(f);
  unsigned r = (u + 0x7FFFu + ((u >> 16) & 1u)) >> 16;
  return (ushort_t)r;
}
DEVINL float bf2f(ushort_t h) { return __uint_as_float(((unsigned)h) << 16); }

DEVINL void packbf16x8(const float* f, uint4& hi, uint4& lo) {
  unsigned hh[8], ll[8];
  #pragma unroll
  for (int j = 0; j < 8; ++j) {
    ushort_t h = bf16rne(f[j]);
    hh[j] = h;
    ll[j] = bf16rne(f[j] - bf2f(h));
  }
  hi.x = hh[0] | (hh[1] << 16); hi.y = hh[2] | (hh[3] << 16);
  hi.z = hh[4] | (hh[5] << 16); hi.w = hh[6] | (hh[7] << 16);
  lo.x = ll[0] | (ll[1] << 16); lo.y = ll[2] | (ll[3] << 16);
  lo.z = ll[4] | (ll[5] << 16); lo.w = ll[6] | (ll[7] << 16);
}
DEVINL uint4 packbf16x8s(const float* f) {
  unsigned hh[8];
  #pragma unroll
  for (int j = 0; j < 8; ++j) hh[j] = bf16rne(f[j]);
  uint4 hi;
  hi.x = hh[0] | (hh[1] << 16); hi.y = hh[2] | (hh[3] << 16);
  hi.z = hh[4] | (hh[5] << 16); hi.w = hh[6] | (hh[7] << 16);
  return hi;
}

DEVINL u64 packKey(float v, unsigned idx) {
  unsigned u = __float_as_uint(v);
  u = (u & 0x80000000u) ? ~u : (u | 0x80000000u);
  return ((u64)u << 32) | (0xFFFFFFFFu - idx);
}
DEVINL float keyVal(u64 k) {
  unsigned u = (unsigned)(k >> 32);
  u = (u & 0x80000000u) ? (u & 0x7FFFFFFFu) : ~u;
  return __uint_as_float(u);
}
DEVINL int keyIdx(u64 k) { return (int)(0xFFFFFFFFu - (unsigned)(k & 0xFFFFFFFFull)); }

DEVINL void topMerge(u64& a0, u64& a1, u64& a2, u64& a3,
                     u64 b0, u64 b1, u64 b2, u64 b3) {
  u64 y0 = a0 > b3 ? a0 : b3;
  u64 y1 = a1 > b2 ? a1 : b2;
  u64 y2 = a2 > b1 ? a2 : b1;
  u64 y3 = a3 > b0 ? a3 : b0;
  u64 t;
  t = y0 > y2 ? y0 : y2; y2 = y0 > y2 ? y2 : y0; y0 = t;
  t = y1 > y3 ? y1 : y3; y3 = y1 > y3 ? y3 : y1; y1 = t;
  t = y0 > y1 ? y0 : y1; y1 = y0 > y1 ? y1 : y0; y0 = t;
  t = y2 > y3 ? y2 : y3; y3 = y2 > y3 ? y3 : y2; y2 = t;
  a0 = y0; a1 = y1; a2 = y2; a3 = y3;
}

// ---------- grid barrier (round-4 proven: 2-level, relaxed polls, fences at edges) ----------
DEVINL void gbar(unsigned* bar, int bid) {
  __syncthreads();
  if (threadIdx.x == 0) {
    __threadfence();
    unsigned g = __hip_atomic_load(bar, __ATOMIC_RELAXED, __HIP_MEMORY_SCOPE_AGENT);
    unsigned* grp = bar + 32 + ((bid >> 4) << 4);
    if (__hip_atomic_fetch_add(grp, 1u, __ATOMIC_ACQ_REL, __HIP_MEMORY_SCOPE_AGENT) == 15u) {
      __hip_atomic_store(grp, 0u, __ATOMIC_RELAXED, __HIP_MEMORY_SCOPE_AGENT);
      if (__hip_atomic_fetch_add(bar + 16, 1u, __ATOMIC_ACQ_REL, __HIP_MEMORY_SCOPE_AGENT) == 31u) {
        __hip_atomic_store(bar + 16, 0u, __ATOMIC_RELAXED, __HIP_MEMORY_SCOPE_AGENT);
        __hip_atomic_store(bar, g + 1u, __ATOMIC_RELEASE, __HIP_MEMORY_SCOPE_AGENT);
      }
    }
    while (__hip_atomic_load(bar, __ATOMIC_RELAXED, __HIP_MEMORY_SCOPE_AGENT) == g) {
      __builtin_amdgcn_s_sleep(2);
    }
    __threadfence();
  }
  __syncthreads();
}

DEVINL f32x4 mfbf(bf16x8 a, bf16x8 b, f32x4 c) {
  return __builtin_amdgcn_mfma_f32_16x16x32_bf16(a, b, c, 0, 0, 0);
}

// ---------- prepass: Wout fp32 -> swizzled bf16 single-plane image ----------
__global__ __launch_bounds__(256) void wout_prepass(const float* __restrict__ Wout,
                                                    ushort_t* __restrict__ img) {
  int U = blockIdx.x * 256 + threadIdx.x;
  if (U >= EBLK * 16 * 512) return;
  int unit = U & 511, ch = (U >> 9) & 15, vb = U >> 13;
  int row = unit >> 3, j = unit & 7;
  int v = vb * 64 + row;
  int k = ch * 64 + ((j ^ (row & 7)) << 3);
  const float* s = Wout + (size_t)v * kH + k;
  float4 f0 = *(const float4*)s;
  float4 f1 = *(const float4*)(s + 4);
  float ff[8] = {f0.x, f0.y, f0.z, f0.w, f1.x, f1.y, f1.z, f1.w};
  *(uint4*)(img + (size_t)U * 8) = packbf16x8s(ff);
}

// ---------- prepass: gate weights fp32 -> swizzled bf16 hi/lo images ----------
__global__ __launch_bounds__(256) void gates_prepass(
    const float* __restrict__ Wih0, const float* __restrict__ Whh0,
    const float* __restrict__ Wih1, const float* __restrict__ Whh1,
    ushort_t* __restrict__ imgh, ushort_t* __restrict__ imgl) {
  int U = blockIdx.x * 256 + threadIdx.x;
  if (U >= 2 * 8 * 64 * 4 * 512) return;
  int unit = U & 511;
  int ch = (U >> 9) & 3;
  int nt = (U >> 11) & 63;
  int kc = (U >> 17) & 7;
  int L  = (U >> 20) & 1;
  int row = unit >> 3, j = unit & 7;
  int n = nt * 64 + row;
  bool lowk = kc < 4;
  const float* M = L ? (lowk ? Wih1 : Whh1) : (lowk ? Wih0 : Whh0);
  int k = kc * 256 + ch * 64 + ((j ^ (row & 7)) << 3) - (lowk ? 0 : kH);
  const float* s = M + (size_t)n * kH + k;
  float4 f0 = *(const float4*)s;
  float4 f1 = *(const float4*)(s + 4);
  float ff[8] = {f0.x, f0.y, f0.z, f0.w, f1.x, f1.y, f1.z, f1.w};
  uint4 hi, lo;
  packbf16x8(ff, hi, lo);
  *(uint4*)(imgh + (size_t)U * 8) = hi;
  *(uint4*)(imgl + (size_t)U * 8) = lo;
}

// ---------- gate GEMM phase: block (kc 0..7, nt 0..63): [64b x 64n] over 256k, bf16x3 ----------
DEVINL void gates_phase(int bid, int tid, int preG, int layer,
                        const float* __restrict__ Wx, const float* __restrict__ Wh,
                        const ushort_t* __restrict__ imgGh, const ushort_t* __restrict__ imgGl,
                        const float* __restrict__ emb, const int* last_l,
                        const ushort_t* __restrict__ xaHi, const ushort_t* __restrict__ xaLo,
                        const ushort_t* __restrict__ xbHi, const ushort_t* __restrict__ xbLo,
                        float* __restrict__ P,
                        ushort_t* sXh, ushort_t* sXl, ushort_t* sWh, ushort_t* sWl) {
  const int kc = bid >> 6, nt = bid & 63;
  const int wv = tid >> 6, lane = tid & 63;
  const int l15 = lane & 15, l4 = lane >> 4;
  const int vg = wv & 3, bh2 = wv >> 2;
  const bool lowk = kc < 4;
  const bool xcvt = lowk && (emb != nullptr);
  const int row = tid >> 3, j = tid & 7;
  const int swz = (j ^ (row & 7)) << 3;
  f32x4 acc[2];
  #pragma unroll
  for (int mt = 0; mt < 2; ++mt) acc[mt] = (f32x4){0.f, 0.f, 0.f, 0.f};

  struct Regs { uint4 xh, xl, wh, wl; float xf[8]; float wf[8]; };
  Regs ra, rb;

  auto loadC = [&](Regs& r, int ch) {
    const int kk = kc * 256 + ch * 64;
    const int ksrc = lowk ? kk : kk - kH;
    if (xcvt) {
      const float* s = emb + (size_t)last_l[row] * kH + kk + swz;
      float4 a0 = *(const float4*)s; float4 a1 = *(const float4*)(s + 4);
      r.xf[0]=a0.x; r.xf[1]=a0.y; r.xf[2]=a0.z; r.xf[3]=a0.w;
      r.xf[4]=a1.x; r.xf[5]=a1.y; r.xf[6]=a1.z; r.xf[7]=a1.w;
    } else {
      const ushort_t* ph = lowk ? xaHi : xbHi;
      const ushort_t* pl = lowk ? xaLo : xbLo;
      size_t go = (size_t)row * kH + ksrc + swz;
      r.xh = *(const uint4*)(ph + go);
      r.xl = *(const uint4*)(pl + go);
    }
    if (preG) {
      size_t ib = (((((size_t)layer * 8 + kc) * 64 + nt) * 4 + ch) * 512 + tid) * 8;
      r.wh = *(const uint4*)(imgGh + ib);
      r.wl = *(const uint4*)(imgGl + ib);
    } else {
      const float* M = lowk ? Wx : Wh;
      const float* s = M + (size_t)(nt * 64 + row) * kH + ksrc + swz;
      float4 a0 = *(const float4*)s; float4 a1 = *(const float4*)(s + 4);
      r.wf[0]=a0.x; r.wf[1]=a0.y; r.wf[2]=a0.z; r.wf[3]=a0.w;
      r.wf[4]=a1.x; r.wf[5]=a1.y; r.wf[6]=a1.z; r.wf[7]=a1.w;
    }
  };
  auto stageC = [&](Regs& r) {
    uint4 vh = r.xh, vl = r.xl;
    if (xcvt) packbf16x8(r.xf, vh, vl);
    *(uint4*)&sXh[tid * 8] = vh;
    *(uint4*)&sXl[tid * 8] = vl;
    uint4 wh = r.wh, wl = r.wl;
    if (!preG) packbf16x8(r.wf, wh, wl);
    *(uint4*)&sWh[tid * 8] = wh;
    *(uint4*)&sWl[tid * 8] = wl;
  };
  auto mfmaC = [&]() {
    #pragma unroll
    for (int ks2 = 0; ks2 < 2; ++ks2) {
      bf16x8 ah[2], al[2];
      #pragma unroll
      for (int mt = 0; mt < 2; ++mt) {
        int rr = bh2 * 32 + mt * 16 + l15;
        int off = rr * 64 + (((ks2 * 4 + l4) ^ (rr & 7)) << 3);
        ah[mt] = *(const bf16x8*)&sXh[off];
        al[mt] = *(const bf16x8*)&sXl[off];
      }
      int rn = vg * 16 + l15;
      int offB = rn * 64 + (((ks2 * 4 + l4) ^ (rn & 7)) << 3);
      bf16x8 bh = *(const bf16x8*)&sWh[offB];
      bf16x8 bl = *(const bf16x8*)&sWl[offB];
      #pragma unroll
      for (int mt = 0; mt < 2; ++mt) {
        acc[mt] = mfbf(ah[mt], bh, acc[mt]);
        acc[mt] = mfbf(al[mt], bh, acc[mt]);
        acc[mt] = mfbf(ah[mt], bl, acc[mt]);
      }
    }
  };

  loadC(ra, 0); loadC(rb, 1);
  __syncthreads(); stageC(ra); __syncthreads(); loadC(ra, 2); mfmaC();
  __syncthreads(); stageC(rb); __syncthreads(); loadC(rb, 3); mfmaC();
  __syncthreads(); stageC(ra); __syncthreads(); mfmaC();
  __syncthreads(); stageC(rb); __syncthreads(); mfmaC();

  const int n = nt * 64 + vg * 16 + l15;
  #pragma unroll
  for (int mt = 0; mt < 2; ++mt)
    #pragma unroll
    for (int r = 0; r < 4; ++r) {
      int b = bh2 * 32 + mt * 16 + l4 * 4 + r;
      P[((size_t)kc * kB + b) * kG4 + n] = acc[mt][r];
    }
}

// ---------- elementwise LSTM cell: 64 blocks x 512 thr x 2 units, fp64 ----------
DEVINL void elem_phase2(int bid, int tid, const float* __restrict__ P,
                        const float* __restrict__ bi, const float* __restrict__ bh,
                        float* cs, ushort_t* hhi, ushort_t* hlo, float* hf32s) {
  const int gt0 = bid * 1024 + tid * 2;
  const int b = gt0 >> 10, u0 = gt0 & 1023;
  double s[2][4];
  #pragma unroll
  for (int gi = 0; gi < 4; ++gi) {
    const int n = gi * kH + u0;
    double a0 = (double)bi[n] + (double)bh[n];
    double a1 = (double)bi[n + 1] + (double)bh[n + 1];
    #pragma unroll
    for (int c = 0; c < NKC; ++c) {
      float2 pq = *(const float2*)(P + ((size_t)c * kB + b) * kG4 + n);
      a0 += (double)pq.x; a1 += (double)pq.y;
    }
    s[0][gi] = a0; s[1][gi] = a1;
  }
  float hf[2];
  #pragma unroll
  for (int q = 0; q < 2; ++q) {
    const int gt = gt0 + q;
    double c = (double)cs[gt];
    double ig = 1.0 / (1.0 + exp(-s[q][0]));
    double fg = 1.0 / (1.0 + exp(-s[q][1]));
    double gg = tanh(s[q][2]);
    double og = 1.0 / (1.0 + exp(-s[q][3]));
    double cn = fg * c + ig * gg;
    cs[gt] = (float)cn;
    hf[q] = (float)(og * tanh(cn));
  }
  ushort_t h0 = bf16rne(hf[0]), h1 = bf16rne(hf[1]);
  *((unsigned*)hhi + (gt0 >> 1)) = (unsigned)h0 | ((unsigned)h1 << 16);
  ushort_t l0 = bf16rne(hf[0] - bf2f(h0)), l1 = bf16rne(hf[1] - bf2f(h1));
  *((unsigned*)hlo + (gt0 >> 1)) = (unsigned)l0 | ((unsigned)l1 << 16);
  if (hf32s) *(float2*)(hf32s + gt0) = make_float2(hf[0], hf[1]);
}

__global__ __launch_bounds__(NTHR, 4) void stack_lstm_persistent(
    const float* __restrict__ hidden, const float* __restrict__ emb,
    const float* __restrict__ Wih0, const float* __restrict__ Whh0,
    const float* __restrict__ bih0, const float* __restrict__ bhh0,
    const float* __restrict__ Wih1, const float* __restrict__ Whh1,
    const float* __restrict__ bih1, const float* __restrict__ bhh1,
    const float* __restrict__ Wout, const float* __restrict__ bout,
    float* __restrict__ out, int T, int preV, int preG, WsPtrs ws) {
  __shared__ ushort_t sXh[64 * 64], sXl[64 * 64];   // 8KB + 8KB
  __shared__ ushort_t sWh[64 * 64], sWl[64 * 64];   // 8KB + 8KB
  __shared__ u64 sRed[1024];                        // 8KB
  __shared__ int last_l[kB];

  const int tid = threadIdx.x;
  const int bid = blockIdx.x;
  const int wv = tid >> 6, lane = tid & 63;
  const int l15 = lane & 15, l4 = lane >> 4;
  const int vg = wv & 3, bh2 = wv >> 2;

  // ---- init state (same mapping as elem so c stays block-private) ----
  if (bid < 64) {
    const int gt0 = bid * 1024 + tid * 2;
    float2 h0p = *(const float2*)(hidden + gt0);
    float2 h1p = *(const float2*)(hidden + kB * kH + gt0);
    ushort_t a = bf16rne(h0p.x), b2 = bf16rne(h0p.y);
    *((unsigned*)ws.h0hi + (gt0 >> 1)) = (unsigned)a | ((unsigned)b2 << 16);
    ushort_t la = bf16rne(h0p.x - bf2f(a)), lb = bf16rne(h0p.y - bf2f(b2));
    *((unsigned*)ws.h0lo + (gt0 >> 1)) = (unsigned)la | ((unsigned)lb << 16);
    a = bf16rne(h1p.x); b2 = bf16rne(h1p.y);
    *((unsigned*)ws.h1hi + (gt0 >> 1)) = (unsigned)a | ((unsigned)b2 << 16);
    la = bf16rne(h1p.x - bf2f(a)); lb = bf16rne(h1p.y - bf2f(b2));
    *((unsigned*)ws.h1lo + (gt0 >> 1)) = (unsigned)la | ((unsigned)lb << 16);
    *(float2*)(ws.h1s + gt0) = make_float2(h1p.x, h1p.y);
    *(float2*)(ws.c0s + gt0) = make_float2(0.f, 0.f);
    *(float2*)(ws.c1s + gt0) = make_float2(0.f, 0.f);
  }
  gbar(ws.bar, bid);

  #pragma unroll 1
  for (int t = 0; t < T; ++t) {
    // ===== A: layer-0 gates -> P =====
    if (tid < kB) last_l[tid] = (t == 0) ? START_INDEX : ws.lastArr[(t - 1) * kB + tid];
    __syncthreads();
    gates_phase(bid, tid, preG, 0, Wih0, Whh0, ws.imgGh, ws.imgGl,
                emb, last_l, nullptr, nullptr, ws.h0hi, ws.h0lo,
                ws.P, sXh, sXl, sWh, sWl);
    gbar(ws.bar, bid);

    // ===== B: elem0 =====
    if (bid < 64)
      elem_phase2(bid, tid, ws.P, bih0, bhh0, ws.c0s, ws.h0hi, ws.h0lo, nullptr);
    gbar(ws.bar, bid);

    // ===== C: layer-1 gates -> P =====
    gates_phase(bid, tid, preG, 1, Wih1, Whh1, ws.imgGh, ws.imgGl,
                nullptr, last_l, ws.h0hi, ws.h0lo, ws.h1hi, ws.h1lo,
                ws.P, sXh, sXl, sWh, sWl);
    gbar(ws.bar, bid);

    // ===== D: elem1 =====
    if (bid < 64)
      elem_phase2(bid, tid, ws.P, bih1, bhh1, ws.c1s, ws.h1hi, ws.h1lo, ws.h1s);
    gbar(ws.bar, bid);

    // ===== E: logits [64b x 64v] per block, bf16 single x single, top-4 =====
    if (bid < EBLK) {
      const int v0 = bid * 64;
      f32x4 acc2[2];
      acc2[0] = (f32x4){0.f, 0.f, 0.f, 0.f};
      acc2[1] = (f32x4){0.f, 0.f, 0.f, 0.f};
      const int row = tid >> 3, j = tid & 7;
      const int swz = (j ^ (row & 7)) << 3;

      struct ERegs { uint4 xh, w; float wf[8]; };
      ERegs ra, rb;
      auto loadE = [&](ERegs& r, int ch) {
        r.xh = *(const uint4*)(ws.h1hi + (size_t)row * kH + ch * 64 + swz);
        if (preV) {
          r.w = *(const uint4*)(ws.imgV + (((size_t)bid * 16 + ch) * 512 + tid) * 8);
        } else {
          const float* s = Wout + (size_t)(v0 + row) * kH + ch * 64 + swz;
          float4 a0 = *(const float4*)s; float4 a1 = *(const float4*)(s + 4);
          r.wf[0]=a0.x; r.wf[1]=a0.y; r.wf[2]=a0.z; r.wf[3]=a0.w;
          r.wf[4]=a1.x; r.wf[5]=a1.y; r.wf[6]=a1.z; r.wf[7]=a1.w;
        }
      };
      auto stageE = [&](ERegs& r) {
        *(uint4*)&sXh[tid * 8] = r.xh;
        uint4 w = r.w;
        if (!preV) w = packbf16x8s(r.wf);
        *(uint4*)&sWh[tid * 8] = w;
      };
      auto mfmaE = [&]() {
        #pragma unroll
        for (int ks2 = 0; ks2 < 2; ++ks2) {
          bf16x8 ah[2];
          #pragma unroll
          for (int mt = 0; mt < 2; ++mt) {
            int rr = bh2 * 32 + mt * 16 + l15;
            int off = rr * 64 + (((ks2 * 4 + l4) ^ (rr & 7)) << 3);
            ah[mt] = *(const bf16x8*)&sXh[off];
          }
          int rn = vg * 16 + l15;
          int offB = rn * 64 + (((ks2 * 4 + l4) ^ (rn & 7)) << 3);
          bf16x8 bw = *(const bf16x8*)&sWh[offB];
          #pragma unroll
          for (int mt = 0; mt < 2; ++mt)
            acc2[mt] = mfbf(ah[mt], bw, acc2[mt]);
        }
      };

      loadE(ra, 0); loadE(rb, 1);
      #pragma unroll 1
      for (int c = 0; c < 16; c += 2) {
        __syncthreads(); stageE(ra); __syncthreads();
        if (c + 2 < 16) loadE(ra, c + 2);
        mfmaE();
        __syncthreads(); stageE(rb); __syncthreads();
        if (c + 3 < 16) loadE(rb, c + 3);
        mfmaE();
      }

      // epilogue: bias, nontemporal store, per-row top-4
      const unsigned vcol = v0 + vg * 16 + l15;
      float bo = bout[vcol];
      #pragma unroll
      for (int mt = 0; mt < 2; ++mt) {
        #pragma unroll
        for (int r = 0; r < 4; ++r) {
          float val = acc2[mt][r] + bo;
          int b = bh2 * 32 + mt * 16 + l4 * 4 + r;
          __builtin_nontemporal_store(val, &out[((size_t)b * T + t) * kV + vcol]);
          u64 t0 = packKey(val, vcol), t1 = 0, t2 = 0, t3 = 0;
          #pragma unroll
          for (int m = 1; m < 16; m <<= 1) {
            u64 o0 = __shfl_xor(t0, m, 16);
            u64 o1 = __shfl_xor(t1, m, 16);
            u64 o2 = __shfl_xor(t2, m, 16);
            u64 o3 = __shfl_xor(t3, m, 16);
            topMerge(t0, t1, t2, t3, o0, o1, o2, o3);
          }
          if (l15 == 0) {
            u64* d = &sRed[((size_t)b * 4 + vg) * 4];
            d[0] = t0; d[1] = t1; d[2] = t2; d[3] = t3;
          }
        }
      }
      __syncthreads();
      if (tid < kB) {
        const u64* s0 = &sRed[(size_t)tid * 16];
        u64 a0 = s0[0], a1 = s0[1], a2 = s0[2], a3 = s0[3];
        #pragma unroll
        for (int g = 1; g < 4; ++g)
          topMerge(a0, a1, a2, a3, s0[g * 4], s0[g * 4 + 1], s0[g * 4 + 2], s0[g * 4 + 3]);
        u64* d = ws.btop + ((size_t)tid * EBLK + bid) * 4;
        d[0] = a0; d[1] = a1; d[2] = a2; d[3] = a3;
      }
    }
    gbar(ws.bar, bid);

    // ===== F: global top-4 + exact fp64 rescue -> lastArr =====
    if (bid < kB) {
      const int b = bid;
      u64 a0 = 0, a1 = 0, a2 = 0, a3 = 0;
      if (tid < EBLK) {
        const u64* s = ws.btop + ((size_t)b * EBLK + tid) * 4;
        a0 = s[0]; a1 = s[1]; a2 = s[2]; a3 = s[3];
      }
      #pragma unroll
      for (int m = 1; m < 64; m <<= 1) {
        u64 o0 = __shfl_xor(a0, m, 64);
        u64 o1 = __shfl_xor(a1, m, 64);
        u64 o2 = __shfl_xor(a2, m, 64);
        u64 o3 = __shfl_xor(a3, m, 64);
        topMerge(a0, a1, a2, a3, o0, o1, o2, o3);
      }
      if (lane == 0) {
        u64* d = &sRed[wv * 4];
        d[0] = a0; d[1] = a1; d[2] = a2; d[3] = a3;
      }
      __syncthreads();
      if (tid == 0) {
        u64 f0 = sRed[0], f1 = sRed[1], f2 = sRed[2], f3 = sRed[3];
        #pragma unroll
        for (int w = 1; w < 8; ++w)
          topMerge(f0, f1, f2, f3, sRed[w * 4], sRed[w * 4 + 1], sRed[w * 4 + 2], sRed[w * 4 + 3]);
        sRed[520] = f0; sRed[521] = f1; sRed[522] = f2; sRed[523] = f3;
        sRed[524] = (keyVal(f0) - keyVal(f1) < GAP_TRIG) ? 1ull : 0ull;
      }
      __syncthreads();
      u64 f0 = sRed[520], f1 = sRed[521], f2 = sRed[522], f3 = sRed[523];
      bool resc = sRed[524] != 0ull;
      __syncthreads();
      if (!resc) {
        if (tid == 0) ws.lastArr[t * kB + b] = keyIdx(f0);
      } else {
        int cand = tid >> 7, jj = tid & 127;
        int ci;
        if (cand == 0) ci = keyIdx(f0);
        else if (cand == 1) ci = keyIdx(f1);
        else if (cand == 2) ci = keyIdx(f2);
        else ci = keyIdx(f3);
        double s = 0.0;
        const float* h = ws.h1s + (size_t)b * kH;
        const float* wr = Wout + (size_t)ci * kH;
        #pragma unroll
        for (int q = 0; q < 8; ++q) {
          int u = jj * 8 + q;
          s += (double)h[u] * (double)wr[u];
        }
        double* sD = (double*)sRed;
        sD[cand * 128 + jj] = s;
        __syncthreads();
        for (int st = 64; st > 0; st >>= 1) {
          if (jj < st) sD[cand * 128 + jj] += sD[cand * 128 + jj + st];
          __syncthreads();
        }
        if (tid == 0) {
          float v1 = keyVal(f0);
          double best = sD[0] + (double)bout[keyIdx(f0)];
          int bi = keyIdx(f0);
          {
            double d = sD[128] + (double)bout[keyIdx(f1)];
            int i = keyIdx(f1);
            if (d > best || (d == best && i < bi)) { best = d; bi = i; }
          }
          if (keyVal(f2) > v1 - CAND_THR) {
            double d = sD[256] + (double)bout[keyIdx(f2)];
            int i = keyIdx(f2);
            if (d > best || (d == best && i < bi)) { best = d; bi = i; }
          }
          if (keyVal(f3) > v1 - CAND_THR) {
            double d = sD[384] + (double)bout[keyIdx(f3)];
            int i = keyIdx(f3);
            if (d > best || (d == best && i < bi)) { best = d; bi = i; }
          }
          ws.lastArr[t * kB + b] = bi;
        }
      }
    }
    gbar(ws.bar, bid);
  }
}

extern "C" void kernel_launch(void* const* d_in, const int* in_sizes, int n_in,
                              void* d_out, int out_size, void* d_ws, size_t ws_size,
                              hipStream_t stream) {
  (void)in_sizes; (void)n_in;
  const float* hidden = (const float*)d_in[0];
  const float* emb    = (const float*)d_in[1];
  const float* Wih0   = (const float*)d_in[2];
  const float* Whh0   = (const float*)d_in[3];
  const float* bih0   = (const float*)d_in[4];
  const float* bhh0   = (const float*)d_in[5];
  const float* Wih1   = (const float*)d_in[6];
  const float* Whh1   = (const float*)d_in[7];
  const float* bih1   = (const float*)d_in[8];
  const float* bhh1   = (const float*)d_in[9];
  const float* Wout   = (const float*)d_in[10];
  const float* bout   = (const float*)d_in[11];
  float* out = (float*)d_out;

  const int T = out_size / (kB * kV);
  if (T <= 0) return;

  char* w = (char*)d_ws;
  WsPtrs ws;
  ws.P      = (float*)w;    w += (size_t)NKC * kB * kG4 * 4;   // 8.39 MB
  ws.c0s    = (float*)w;    w += (size_t)kB * kH * 4;
  ws.c1s    = (float*)w;    w += (size_t)kB * kH * 4;
  ws.h1s    = (float*)w;    w += (size_t)kB * kH * 4;
  ws.h0hi   = (ushort_t*)w; w += (size_t)kB * kH * 2;
  ws.h0lo   = (ushort_t*)w; w += (size_t)kB * kH * 2;
  ws.h1hi   = (ushort_t*)w; w += (size_t)kB * kH * 2;
  ws.h1lo   = (ushort_t*)w; w += (size_t)kB * kH * 2;
  ws.btop   = (u64*)w;      w += (size_t)kB * EBLK * 4 * 8;    // 1.02 MB
  ws.lastArr = (int*)w;     w += (size_t)T * kB * 4;
  uintptr_t a = ((uintptr_t)w + 127) & ~(uintptr_t)127;
  ws.bar = (unsigned*)a;
  char* p = (char*)a + 16384;

  const size_t vBytes = (size_t)EBLK * 16 * 512 * 8 * 2;        // 65.5 MB
  const size_t gBytes = (size_t)2 * 8 * 64 * 4 * 512 * 8 * 2;   // 33.6 MB each
  ws.imgV = (ushort_t*)p;
  int preV = (ws_size >= (size_t)(p - (char*)d_ws) + vBytes + (1u << 20)) ? 1 : 0;
  if (preV) p += vBytes;
  ws.imgGh = (ushort_t*)p;
  ws.imgGl = (ushort_t*)(p + gBytes);
  int preG = (ws_size >= (size_t)(p - (char*)d_ws) + 2 * gBytes + (1u << 20)) ? 1 : 0;

  hipMemsetAsync((void*)ws.bar, 0, 16384, stream);
  if (preV) {
    int units = EBLK * 16 * 512;
    hipLaunchKernelGGL(wout_prepass, dim3((units + 255) / 256), dim3(256), 0, stream,
                       Wout, ws.imgV);
  }
  if (preG) {
    int units = 2 * 8 * 64 * 4 * 512;
    hipLaunchKernelGGL(gates_prepass, dim3((units + 255) / 256), dim3(256), 0, stream,
                       Wih0, Whh0, Wih1, Whh1, ws.imgGh, ws.imgGl);
  }
  hipLaunchKernelGGL(stack_lstm_persistent, dim3(NBLK), dim3(NTHR), 0, stream,
                     hidden, emb, Wih0, Whh0, bih0, bhh0,
                     Wih1, Whh1, bih1, bhh1, Wout, bout,
                     out, T, preV, preG, ws);
}

// Round 7
// 10461.961 us; speedup vs baseline: 4.0431x; 1.8611x over previous
//
#include <hip/hip_runtime.h>
#include <cstdint>
#include <cstddef>

#define DEVINL __device__ __forceinline__

typedef unsigned short ushort_t;
typedef unsigned long long u64;
typedef __attribute__((ext_vector_type(8))) short bf16x8;
typedef __attribute__((ext_vector_type(4))) float f32x4;

namespace {
constexpr int kB = 64, kH = 1024, kV = 32000;
constexpr int NBLK = 512, NTHR = 512;
constexpr int GBLK = 256;        // gate blocks: each owns 4 units (16 cols over 4 gates)
constexpr int EBLK = 500;        // logits blocks: 64 vocab cols each
constexpr int START_INDEX = 1;
constexpr float GAP_TRIG = 4e-3f;
constexpr float CAND_THR = 2e-3f;
}

struct WsPtrs {
  float *c0s, *c1s, *h1s;
  ushort_t *h0fh0, *h0fh1, *h0fl0, *h0fl1;   // h0 fragment images, hi/lo, parity 0/1
  ushort_t *h1fh0, *h1fh1, *h1fl0, *h1fl1;   // h1 fragment images
  u64* btop;                                  // [64][500][4]
  int* lastArr;                               // [T][64]
  unsigned* bar;
  ushort_t *imgV, *imgGh, *imgGl;             // fragment-ordered weight images
};

// ---------- numeric helpers ----------
DEVINL ushort_t bf16rne(float f) {
  unsigned u = __float_as_uint(f);
  unsigned r = (u + 0x7FFFu + ((u >> 16) & 1u)) >> 16;
  return (ushort_t)r;
}
DEVINL float bf2f(ushort_t h) { return __uint_as_float(((unsigned)h) << 16); }

DEVINL void packbf16x8(const float* f, uint4& hi, uint4& lo) {
  unsigned hh[8], ll[8];
  #pragma unroll
  for (int j = 0; j < 8; ++j) {
    ushort_t h = bf16rne(f[j]);
    hh[j] = h;
    ll[j] = bf16rne(f[j] - bf2f(h));
  }
  hi.x = hh[0] | (hh[1] << 16); hi.y = hh[2] | (hh[3] << 16);
  hi.z = hh[4] | (hh[5] << 16); hi.w = hh[6] | (hh[7] << 16);
  lo.x = ll[0] | (ll[1] << 16); lo.y = ll[2] | (ll[3] << 16);
  lo.z = ll[4] | (ll[5] << 16); lo.w = ll[6] | (ll[7] << 16);
}
DEVINL uint4 packbf16x8s(const float* f) {
  unsigned hh[8];
  #pragma unroll
  for (int j = 0; j < 8; ++j) hh[j] = bf16rne(f[j]);
  uint4 hi;
  hi.x = hh[0] | (hh[1] << 16); hi.y = hh[2] | (hh[3] << 16);
  hi.z = hh[4] | (hh[5] << 16); hi.w = hh[6] | (hh[7] << 16);
  return hi;
}
DEVINL bf16x8 asbf(uint4 v) { union { uint4 u; bf16x8 b; } c; c.u = v; return c.b; }

DEVINL u64 packKey(float v, unsigned idx) {
  unsigned u = __float_as_uint(v);
  u = (u & 0x80000000u) ? ~u : (u | 0x80000000u);
  return ((u64)u << 32) | (0xFFFFFFFFu - idx);
}
DEVINL float keyVal(u64 k) {
  unsigned u = (unsigned)(k >> 32);
  u = (u & 0x80000000u) ? (u & 0x7FFFFFFFu) : ~u;
  return __uint_as_float(u);
}
DEVINL int keyIdx(u64 k) { return (int)(0xFFFFFFFFu - (unsigned)(k & 0xFFFFFFFFull)); }

DEVINL void topMerge(u64& a0, u64& a1, u64& a2, u64& a3,
                     u64 b0, u64 b1, u64 b2, u64 b3) {
  u64 y0 = a0 > b3 ? a0 : b3;
  u64 y1 = a1 > b2 ? a1 : b2;
  u64 y2 = a2 > b1 ? a2 : b1;
  u64 y3 = a3 > b0 ? a3 : b0;
  u64 t;
  t = y0 > y2 ? y0 : y2; y2 = y0 > y2 ? y2 : y0; y0 = t;
  t = y1 > y3 ? y1 : y3; y3 = y1 > y3 ? y3 : y1; y1 = t;
  t = y0 > y1 ? y0 : y1; y1 = y0 > y1 ? y1 : y0; y0 = t;
  t = y2 > y3 ? y2 : y3; y3 = y2 > y3 ? y3 : y2; y2 = t;
  a0 = y0; a1 = y1; a2 = y2; a3 = y3;
}

// ---------- grid barrier (round-4/6 proven) ----------
DEVINL void gbar(unsigned* bar, int bid) {
  __syncthreads();
  if (threadIdx.x == 0) {
    __threadfence();
    unsigned g = __hip_atomic_load(bar, __ATOMIC_RELAXED, __HIP_MEMORY_SCOPE_AGENT);
    unsigned* grp = bar + 32 + ((bid >> 4) << 4);
    if (__hip_atomic_fetch_add(grp, 1u, __ATOMIC_ACQ_REL, __HIP_MEMORY_SCOPE_AGENT) == 15u) {
      __hip_atomic_store(grp, 0u, __ATOMIC_RELAXED, __HIP_MEMORY_SCOPE_AGENT);
      if (__hip_atomic_fetch_add(bar + 16, 1u, __ATOMIC_ACQ_REL, __HIP_MEMORY_SCOPE_AGENT) == 31u) {
        __hip_atomic_store(bar + 16, 0u, __ATOMIC_RELAXED, __HIP_MEMORY_SCOPE_AGENT);
        __hip_atomic_store(bar, g + 1u, __ATOMIC_RELEASE, __HIP_MEMORY_SCOPE_AGENT);
      }
    }
    while (__hip_atomic_load(bar, __ATOMIC_RELAXED, __HIP_MEMORY_SCOPE_AGENT) == g) {
      __builtin_amdgcn_s_sleep(2);
    }
    __threadfence();
  }
  __syncthreads();
}

DEVINL f32x4 mfbf(bf16x8 a, bf16x8 b, f32x4 c) {
  return __builtin_amdgcn_mfma_f32_16x16x32_bf16(a, b, c, 0, 0, 0);
}

// ---------- prepass: gate weights -> fragment-ordered bf16 hi/lo image ----------
// layout: [L][jb 0..255][ks 0..63][lane 0..63][8]; col lc=l15: g=lc>>2, u=jb*4+(lc&3); k=ks*32+l4*8
__global__ __launch_bounds__(256) void gates_prepass(
    const float* __restrict__ Wih0, const float* __restrict__ Whh0,
    const float* __restrict__ Wih1, const float* __restrict__ Whh1,
    ushort_t* __restrict__ imgh, ushort_t* __restrict__ imgl) {
  int U = blockIdx.x * 256 + threadIdx.x;
  if (U >= 2 * GBLK * 64 * 64) return;
  int lane = U & 63, ks = (U >> 6) & 63, jb = (U >> 12) & 255, L = U >> 20;
  int l15 = lane & 15, l4 = lane >> 4;
  int n = (l15 >> 2) * kH + jb * 4 + (l15 & 3);
  int k = ks * 32 + l4 * 8;
  const float* M = (k < kH) ? (L ? Wih1 : Wih0) : (L ? Whh1 : Whh0);
  const float* s = M + (size_t)n * kH + (k & (kH - 1));
  float4 f0 = *(const float4*)s;
  float4 f1 = *(const float4*)(s + 4);
  float ff[8] = {f0.x, f0.y, f0.z, f0.w, f1.x, f1.y, f1.z, f1.w};
  uint4 hi, lo;
  packbf16x8(ff, hi, lo);
  *(uint4*)(imgh + (size_t)U * 8) = hi;
  *(uint4*)(imgl + (size_t)U * 8) = lo;
}

// ---------- prepass: Wout -> fragment-ordered bf16 single image ----------
// layout: [eb 0..499][vg 0..3][ks 0..31][lane][8]; col v=eb*64+vg*16+l15; k=ks*32+l4*8
__global__ __launch_bounds__(256) void wout_prepass(const float* __restrict__ Wout,
                                                    ushort_t* __restrict__ img) {
  int U = blockIdx.x * 256 + threadIdx.x;
  if (U >= EBLK * 4 * 32 * 64) return;
  int lane = U & 63, ks = (U >> 6) & 31, vg = (U >> 11) & 3, eb = U >> 13;
  int v = eb * 64 + vg * 16 + (lane & 15);
  int k = ks * 32 + (lane >> 4) * 8;
  const float* s = Wout + (size_t)v * kH + k;
  float4 f0 = *(const float4*)s;
  float4 f1 = *(const float4*)(s + 4);
  float ff[8] = {f0.x, f0.y, f0.z, f0.w, f1.x, f1.y, f1.z, f1.w};
  *(uint4*)(img + (size_t)U * 8) = packbf16x8s(ff);
}

// ---------- fused gates GEMM + LSTM cell for one layer ----------
// block jb: cols {g*1024 + jb*4 + 0..3, g=0..3} (=16), all 64 b, K=2048.
// waves: mt=wv&3 (16 rows), kv=wv>>2 (K half). x1 = kv0 source (null => emb), x2 = kv1 source.
DEVINL void gates_elem(int jb, int tid, int L, int preG,
                       const float* __restrict__ emb, const int* last_l,
                       const ushort_t* __restrict__ x1h, const ushort_t* __restrict__ x1l,
                       const ushort_t* __restrict__ x2h, const ushort_t* __restrict__ x2l,
                       const ushort_t* __restrict__ imgGh, const ushort_t* __restrict__ imgGl,
                       const float* __restrict__ Wx, const float* __restrict__ Wh,
                       const float* __restrict__ bi, const float* __restrict__ bh_,
                       float* __restrict__ cs,
                       ushort_t* __restrict__ wrH, ushort_t* __restrict__ wrL,
                       float* __restrict__ h1s, float* sG2) {
  const int wv = tid >> 6, lane = tid & 63, l15 = lane & 15, l4 = lane >> 4;
  const int mt = wv & 3, kv = wv >> 2;
  f32x4 acc = (f32x4){0.f, 0.f, 0.f, 0.f};
  const size_t wbase = ((((size_t)L * GBLK + jb) * 64 + kv * 32) * 64 + lane) * 8;

  if (preG) {
    if (kv == 0 && x1h == nullptr) {
      const float* es = emb + (size_t)last_l[mt * 16 + l15] * kH + l4 * 8;
      #pragma unroll 2
      for (int s = 0; s < 32; ++s) {
        float4 a0 = *(const float4*)(es + s * 32);
        float4 a1 = *(const float4*)(es + s * 32 + 4);
        float ff[8] = {a0.x, a0.y, a0.z, a0.w, a1.x, a1.y, a1.z, a1.w};
        uint4 h, l; packbf16x8(ff, h, l);
        bf16x8 ah = asbf(h), al = asbf(l);
        bf16x8 bh = *(const bf16x8*)(imgGh + wbase + (size_t)s * 512);
        bf16x8 bl = *(const bf16x8*)(imgGl + wbase + (size_t)s * 512);
        acc = mfbf(ah, bh, acc); acc = mfbf(al, bh, acc); acc = mfbf(ah, bl, acc);
      }
    } else {
      const ushort_t* xh = kv ? x2h : x1h;
      const ushort_t* xl = kv ? x2l : x1l;
      const size_t xb = ((size_t)(mt * 32) * 64 + lane) * 8;
      #pragma unroll 4
      for (int s = 0; s < 32; ++s) {
        bf16x8 ah = *(const bf16x8*)(xh + xb + (size_t)s * 512);
        bf16x8 al = *(const bf16x8*)(xl + xb + (size_t)s * 512);
        bf16x8 bh = *(const bf16x8*)(imgGh + wbase + (size_t)s * 512);
        bf16x8 bl = *(const bf16x8*)(imgGl + wbase + (size_t)s * 512);
        acc = mfbf(ah, bh, acc); acc = mfbf(al, bh, acc); acc = mfbf(ah, bl, acc);
      }
    }
  } else {
    const int n = (l15 >> 2) * kH + jb * 4 + (l15 & 3);
    const float* wsrc = (kv ? Wh : Wx) + (size_t)n * kH + l4 * 8;
    if (kv == 0 && x1h == nullptr) {
      const float* es = emb + (size_t)last_l[mt * 16 + l15] * kH + l4 * 8;
      #pragma unroll 2
      for (int s = 0; s < 32; ++s) {
        float4 a0 = *(const float4*)(es + s * 32);
        float4 a1 = *(const float4*)(es + s * 32 + 4);
        float xf[8] = {a0.x, a0.y, a0.z, a0.w, a1.x, a1.y, a1.z, a1.w};
        float4 w0 = *(const float4*)(wsrc + s * 32);
        float4 w1 = *(const float4*)(wsrc + s * 32 + 4);
        float wf[8] = {w0.x, w0.y, w0.z, w0.w, w1.x, w1.y, w1.z, w1.w};
        uint4 xh4, xl4, wh4, wl4;
        packbf16x8(xf, xh4, xl4);
        packbf16x8(wf, wh4, wl4);
        bf16x8 ah = asbf(xh4), al = asbf(xl4), bh = asbf(wh4), bl = asbf(wl4);
        acc = mfbf(ah, bh, acc); acc = mfbf(al, bh, acc); acc = mfbf(ah, bl, acc);
      }
    } else {
      const ushort_t* xh = kv ? x2h : x1h;
      const ushort_t* xl = kv ? x2l : x1l;
      const size_t xb = ((size_t)(mt * 32) * 64 + lane) * 8;
      #pragma unroll 2
      for (int s = 0; s < 32; ++s) {
        bf16x8 ah = *(const bf16x8*)(xh + xb + (size_t)s * 512);
        bf16x8 al = *(const bf16x8*)(xl + xb + (size_t)s * 512);
        float4 w0 = *(const float4*)(wsrc + s * 32);
        float4 w1 = *(const float4*)(wsrc + s * 32 + 4);
        float wf[8] = {w0.x, w0.y, w0.z, w0.w, w1.x, w1.y, w1.z, w1.w};
        uint4 wh4, wl4;
        packbf16x8(wf, wh4, wl4);
        bf16x8 bh = asbf(wh4), bl = asbf(wl4);
        acc = mfbf(ah, bh, acc); acc = mfbf(al, bh, acc); acc = mfbf(ah, bl, acc);
      }
    }
  }

  // exchange: sG2[kv][b 0..63][lc 0..15]
  #pragma unroll
  for (int r = 0; r < 4; ++r) {
    int b = mt * 16 + l4 * 4 + r;
    sG2[(kv * kB + b) * 16 + l15] = acc[r];
  }
  __syncthreads();

  if (tid < 256) {
    int b = tid >> 2, uu = tid & 3;
    int u = jb * 4 + uu;
    double gv[4];
    #pragma unroll
    for (int g = 0; g < 4; ++g) {
      int lc = g * 4 + uu;
      int n = g * kH + u;
      gv[g] = (double)sG2[b * 16 + lc] + (double)sG2[(kB + b) * 16 + lc]
            + (double)bi[n] + (double)bh_[n];
    }
    int co = jb * 256 + tid;
    double c = (double)cs[co];
    double ig = 1.0 / (1.0 + exp(-gv[0]));
    double fg = 1.0 / (1.0 + exp(-gv[1]));
    double gg = tanh(gv[2]);
    double og = 1.0 / (1.0 + exp(-gv[3]));
    double cn = fg * c + ig * gg;
    cs[co] = (float)cn;
    float hf = (float)(og * tanh(cn));
    ushort_t hb = bf16rne(hf);
    ushort_t lb = bf16rne(hf - bf2f(hb));
    size_t fo = (size_t)(((b >> 4) * 32 + (u >> 5)) * 64 + ((u >> 3) & 3) * 16 + (b & 15)) * 8 + (u & 7);
    wrH[fo] = hb;
    wrL[fo] = lb;
    if (h1s) h1s[(size_t)b * kH + u] = hf;
  }
}

__global__ __launch_bounds__(NTHR, 4) void stack_lstm_persistent(
    const float* __restrict__ hidden, const float* __restrict__ emb,
    const float* __restrict__ Wih0, const float* __restrict__ Whh0,
    const float* __restrict__ bih0, const float* __restrict__ bhh0,
    const float* __restrict__ Wih1, const float* __restrict__ Whh1,
    const float* __restrict__ bih1, const float* __restrict__ bhh1,
    const float* __restrict__ Wout, const float* __restrict__ bout,
    float* __restrict__ out, int T, int preV, int preG, WsPtrs ws) {
  __shared__ float sG2[2 * kB * 16];   // 8KB gate exchange
  __shared__ u64 sRed[1024];           // 8KB (E/F reductions)
  __shared__ int last_l[kB];

  const int tid = threadIdx.x;
  const int bid = blockIdx.x;
  const int wv = tid >> 6, lane = tid & 63;
  const int l15 = lane & 15, l4 = lane >> 4;

  // ---- init: fragment-convert hidden, zero cell states ----
  {
    int idx = bid * NTHR + tid;
    if (idx < 2 * kB * kH) {
      int L = idx >> 16;
      int gt = idx & 65535;
      int b = gt >> 10, u = gt & 1023;
      float hv = hidden[idx];
      ushort_t hb = bf16rne(hv);
      ushort_t lb = bf16rne(hv - bf2f(hb));
      size_t fo = (size_t)(((b >> 4) * 32 + (u >> 5)) * 64 + ((u >> 3) & 3) * 16 + (b & 15)) * 8 + (u & 7);
      int co = (u >> 2) * 256 + b * 4 + (u & 3);
      if (L == 0) {
        ws.h0fh0[fo] = hb; ws.h0fl0[fo] = lb;
        ws.c0s[co] = 0.f;
      } else {
        ws.h1fh0[fo] = hb; ws.h1fl0[fo] = lb;
        ws.h1s[gt] = hv;
        ws.c1s[co] = 0.f;
      }
    }
  }
  gbar(ws.bar, bid);

  #pragma unroll 1
  for (int t = 0; t < T; ++t) {
    const int pr = t & 1;
    ushort_t* h0rdH = pr ? ws.h0fh1 : ws.h0fh0;
    ushort_t* h0rdL = pr ? ws.h0fl1 : ws.h0fl0;
    ushort_t* h0wrH = pr ? ws.h0fh0 : ws.h0fh1;
    ushort_t* h0wrL = pr ? ws.h0fl0 : ws.h0fl1;
    ushort_t* h1rdH = pr ? ws.h1fh1 : ws.h1fh0;
    ushort_t* h1rdL = pr ? ws.h1fl1 : ws.h1fl0;
    ushort_t* h1wrH = pr ? ws.h1fh0 : ws.h1fh1;
    ushort_t* h1wrL = pr ? ws.h1fl0 : ws.h1fl1;

    // ===== A: layer-0 gates+cell ===== / ===== C: layer-1 gates+cell =====
    #pragma unroll 1
    for (int L = 0; L < 2; ++L) {
      if (bid < GBLK) {
        if (L == 0) {
          if (tid < kB)
            last_l[tid] = (t == 0) ? START_INDEX : ws.lastArr[(t - 1) * kB + tid];
          __syncthreads();
        }
        gates_elem(bid, tid, L, preG, emb, last_l,
                   L ? h0wrH : nullptr, L ? h0wrL : nullptr,
                   L ? h1rdH : h0rdH, L ? h1rdL : h0rdL,
                   ws.imgGh, ws.imgGl,
                   L ? Wih1 : Wih0, L ? Whh1 : Whh0,
                   L ? bih1 : bih0, L ? bhh1 : bhh0,
                   L ? ws.c1s : ws.c0s,
                   L ? h1wrH : h0wrH, L ? h1wrL : h0wrL,
                   L ? ws.h1s : nullptr, sG2);
      }
      gbar(ws.bar, bid);
    }

    // ===== E: logits [64b x 64v], streaming fragment GEMM, top-4 =====
    if (bid < EBLK) {
      const int eb = bid, v0 = eb * 64;
      const int bh2 = wv >> 2, vg = wv & 3;
      f32x4 acc2[2];
      acc2[0] = (f32x4){0.f, 0.f, 0.f, 0.f};
      acc2[1] = (f32x4){0.f, 0.f, 0.f, 0.f};
      const size_t xb0 = ((size_t)((bh2 * 2 + 0) * 32) * 64 + lane) * 8;
      const size_t xb1 = ((size_t)((bh2 * 2 + 1) * 32) * 64 + lane) * 8;
      if (preV) {
        const size_t wb = (((size_t)(eb * 4 + vg) * 32) * 64 + lane) * 8;
        #pragma unroll 4
        for (int s = 0; s < 32; ++s) {
          bf16x8 a0 = *(const bf16x8*)(h1wrH + xb0 + (size_t)s * 512);
          bf16x8 a1 = *(const bf16x8*)(h1wrH + xb1 + (size_t)s * 512);
          bf16x8 bw = *(const bf16x8*)(ws.imgV + wb + (size_t)s * 512);
          acc2[0] = mfbf(a0, bw, acc2[0]);
          acc2[1] = mfbf(a1, bw, acc2[1]);
        }
      } else {
        int v = v0 + vg * 16 + l15;
        const float* wsrc = Wout + (size_t)v * kH + l4 * 8;
        #pragma unroll 2
        for (int s = 0; s < 32; ++s) {
          bf16x8 a0 = *(const bf16x8*)(h1wrH + xb0 + (size_t)s * 512);
          bf16x8 a1 = *(const bf16x8*)(h1wrH + xb1 + (size_t)s * 512);
          float4 w0 = *(const float4*)(wsrc + s * 32);
          float4 w1 = *(const float4*)(wsrc + s * 32 + 4);
          float wf[8] = {w0.x, w0.y, w0.z, w0.w, w1.x, w1.y, w1.z, w1.w};
          bf16x8 bw = asbf(packbf16x8s(wf));
          acc2[0] = mfbf(a0, bw, acc2[0]);
          acc2[1] = mfbf(a1, bw, acc2[1]);
        }
      }
      // epilogue: bias, store, per-row top-4
      const unsigned vcol = v0 + vg * 16 + l15;
      float bo = bout[vcol];
      #pragma unroll
      for (int mt = 0; mt < 2; ++mt) {
        #pragma unroll
        for (int r = 0; r < 4; ++r) {
          float val = acc2[mt][r] + bo;
          int b = bh2 * 32 + mt * 16 + l4 * 4 + r;
          __builtin_nontemporal_store(val, &out[((size_t)b * T + t) * kV + vcol]);
          u64 t0 = packKey(val, vcol), t1 = 0, t2 = 0, t3 = 0;
          #pragma unroll
          for (int m = 1; m < 16; m <<= 1) {
            u64 o0 = __shfl_xor(t0, m, 16);
            u64 o1 = __shfl_xor(t1, m, 16);
            u64 o2 = __shfl_xor(t2, m, 16);
            u64 o3 = __shfl_xor(t3, m, 16);
            topMerge(t0, t1, t2, t3, o0, o1, o2, o3);
          }
          if (l15 == 0) {
            u64* d = &sRed[((size_t)b * 4 + vg) * 4];
            d[0] = t0; d[1] = t1; d[2] = t2; d[3] = t3;
          }
        }
      }
      __syncthreads();
      if (tid < kB) {
        const u64* s0 = &sRed[(size_t)tid * 16];
        u64 a0 = s0[0], a1 = s0[1], a2 = s0[2], a3 = s0[3];
        #pragma unroll
        for (int g = 1; g < 4; ++g)
          topMerge(a0, a1, a2, a3, s0[g * 4], s0[g * 4 + 1], s0[g * 4 + 2], s0[g * 4 + 3]);
        u64* d = ws.btop + ((size_t)tid * EBLK + bid) * 4;
        d[0] = a0; d[1] = a1; d[2] = a2; d[3] = a3;
      }
    }
    gbar(ws.bar, bid);

    // ===== F: global top-4 + exact fp64 rescue -> lastArr =====
    if (bid < kB) {
      const int b = bid;
      u64 a0 = 0, a1 = 0, a2 = 0, a3 = 0;
      if (tid < EBLK) {
        const u64* s = ws.btop + ((size_t)b * EBLK + tid) * 4;
        a0 = s[0]; a1 = s[1]; a2 = s[2]; a3 = s[3];
      }
      #pragma unroll
      for (int m = 1; m < 64; m <<= 1) {
        u64 o0 = __shfl_xor(a0, m, 64);
        u64 o1 = __shfl_xor(a1, m, 64);
        u64 o2 = __shfl_xor(a2, m, 64);
        u64 o3 = __shfl_xor(a3, m, 64);
        topMerge(a0, a1, a2, a3, o0, o1, o2, o3);
      }
      if (lane == 0) {
        u64* d = &sRed[wv * 4];
        d[0] = a0; d[1] = a1; d[2] = a2; d[3] = a3;
      }
      __syncthreads();
      if (tid == 0) {
        u64 f0 = sRed[0], f1 = sRed[1], f2 = sRed[2], f3 = sRed[3];
        #pragma unroll
        for (int w = 1; w < 8; ++w)
          topMerge(f0, f1, f2, f3, sRed[w * 4], sRed[w * 4 + 1], sRed[w * 4 + 2], sRed[w * 4 + 3]);
        sRed[520] = f0; sRed[521] = f1; sRed[522] = f2; sRed[523] = f3;
        sRed[524] = (keyVal(f0) - keyVal(f1) < GAP_TRIG) ? 1ull : 0ull;
      }
      __syncthreads();
      u64 f0 = sRed[520], f1 = sRed[521], f2 = sRed[522], f3 = sRed[523];
      bool resc = sRed[524] != 0ull;
      __syncthreads();
      if (!resc) {
        if (tid == 0) ws.lastArr[t * kB + b] = keyIdx(f0);
      } else {
        int cand = tid >> 7, jj = tid & 127;
        int ci;
        if (cand == 0) ci = keyIdx(f0);
        else if (cand == 1) ci = keyIdx(f1);
        else if (cand == 2) ci = keyIdx(f2);
        else ci = keyIdx(f3);
        double s = 0.0;
        const float* h = ws.h1s + (size_t)b * kH;
        const float* wr = Wout + (size_t)ci * kH;
        #pragma unroll
        for (int q = 0; q < 8; ++q) {
          int u = jj * 8 + q;
          s += (double)h[u] * (double)wr[u];
        }
        double* sD = (double*)sRed;
        sD[cand * 128 + jj] = s;
        __syncthreads();
        for (int st = 64; st > 0; st >>= 1) {
          if (jj < st) sD[cand * 128 + jj] += sD[cand * 128 + jj + st];
          __syncthreads();
        }
        if (tid == 0) {
          float v1 = keyVal(f0);
          double best = sD[0] + (double)bout[keyIdx(f0)];
          int bi = keyIdx(f0);
          {
            double d = sD[128] + (double)bout[keyIdx(f1)];
            int i = keyIdx(f1);
            if (d > best || (d == best && i < bi)) { best = d; bi = i; }
          }
          if (keyVal(f2) > v1 - CAND_THR) {
            double d = sD[256] + (double)bout[keyIdx(f2)];
            int i = keyIdx(f2);
            if (d > best || (d == best && i < bi)) { best = d; bi = i; }
          }
          if (keyVal(f3) > v1 - CAND_THR) {
            double d = sD[384] + (double)bout[keyIdx(f3)];
            int i = keyIdx(f3);
            if (d > best || (d == best && i < bi)) { best = d; bi = i; }
          }
          ws.lastArr[t * kB + b] = bi;
        }
      }
    }
    gbar(ws.bar, bid);
  }
}

extern "C" void kernel_launch(void* const* d_in, const int* in_sizes, int n_in,
                              void* d_out, int out_size, void* d_ws, size_t ws_size,
                              hipStream_t stream) {
  (void)in_sizes; (void)n_in;
  const float* hidden = (const float*)d_in[0];
  const float* emb    = (const float*)d_in[1];
  const float* Wih0   = (const float*)d_in[2];
  const float* Whh0   = (const float*)d_in[3];
  const float* bih0   = (const float*)d_in[4];
  const float* bhh0   = (const float*)d_in[5];
  const float* Wih1   = (const float*)d_in[6];
  const float* Whh1   = (const float*)d_in[7];
  const float* bih1   = (const float*)d_in[8];
  const float* bhh1   = (const float*)d_in[9];
  const float* Wout   = (const float*)d_in[10];
  const float* bout   = (const float*)d_in[11];
  float* out = (float*)d_out;

  const int T = out_size / (kB * kV);
  if (T <= 0) return;

  char* w = (char*)d_ws;
  WsPtrs ws;
  ws.c0s = (float*)w; w += (size_t)kB * kH * 4;
  ws.c1s = (float*)w; w += (size_t)kB * kH * 4;
  ws.h1s = (float*)w; w += (size_t)kB * kH * 4;
  const size_t fragB = (size_t)kB * kH * 2;   // 128KB
  ws.h0fh0 = (ushort_t*)w; w += fragB;
  ws.h0fh1 = (ushort_t*)w; w += fragB;
  ws.h0fl0 = (ushort_t*)w; w += fragB;
  ws.h0fl1 = (ushort_t*)w; w += fragB;
  ws.h1fh0 = (ushort_t*)w; w += fragB;
  ws.h1fh1 = (ushort_t*)w; w += fragB;
  ws.h1fl0 = (ushort_t*)w; w += fragB;
  ws.h1fl1 = (ushort_t*)w; w += fragB;
  ws.btop = (u64*)w;  w += (size_t)kB * EBLK * 4 * 8;
  ws.lastArr = (int*)w; w += (size_t)T * kB * 4;
  uintptr_t a = ((uintptr_t)w + 127) & ~(uintptr_t)127;
  ws.bar = (unsigned*)a;
  char* p = (char*)a + 16384;

  const size_t vBytes = (size_t)EBLK * 4 * 32 * 64 * 8 * 2;       // 65.5 MB
  const size_t gBytes = (size_t)2 * GBLK * 64 * 64 * 8 * 2;       // 33.55 MB each
  ws.imgV = (ushort_t*)p;
  int preV = (ws_size >= (size_t)(p - (char*)d_ws) + vBytes + (1u << 20)) ? 1 : 0;
  if (preV) p += vBytes;
  ws.imgGh = (ushort_t*)p;
  ws.imgGl = (ushort_t*)(p + gBytes);
  int preG = (ws_size >= (size_t)(p - (char*)d_ws) + 2 * gBytes + (1u << 20)) ? 1 : 0;

  hipMemsetAsync((void*)ws.bar, 0, 16384, stream);
  if (preV) {
    int units = EBLK * 4 * 32 * 64;
    hipLaunchKernelGGL(wout_prepass, dim3((units + 255) / 256), dim3(256), 0, stream,
                       Wout, ws.imgV);
  }
  if (preG) {
    int units = 2 * GBLK * 64 * 64;
    hipLaunchKernelGGL(gates_prepass, dim3((units + 255) / 256), dim3(256), 0, stream,
                       Wih0, Whh0, Wih1, Whh1, ws.imgGh, ws.imgGl);
  }
  hipLaunchKernelGGL(stack_lstm_persistent, dim3(NBLK), dim3(NTHR), 0, stream,
                     hidden, emb, Wih0, Whh0, bih0, bhh0,
                     Wih1, Whh1, bih1, bhh1, Wout, bout,
                     out, T, preV, preG, ws);
}